// Round 9
// baseline (240.561 us; speedup 1.0000x reference)
//
#include <hip/hip_runtime.h>
#include <math.h>

// PixPro fused masked all-pairs cosine loss, MI355X (gfx950).
// B=2048, C=256, H=W=7 -> P=49 pixels.
// out[b] = -(1/2401) * sum_{p,q} wt[p][q] * dot(base_p, mom_q)/max(nb_p*nm_q, eps)
// wt[p][q] = [base_A[p,q]==1] + [moment_A[q,p]==1].
//
// v10b: global_load_lds staging of raw fp32; hi/lo bf16 conversion at read.
//  (v10 failed to compile: global_load_lds's offset arg must be a literal.
//   Fixed by folding chunk displacements into the global source POINTER and
//   passing offset=0 -- compiler folds the constant add into the instr's
//   13-bit immediate; codegen identical to the v10 intent.)
//  r5-r7 lesson: register-staged prefetch trades VGPRs for latency cover 1:1
//  against residency (v9: VGPR 52->96, occupancy 36->19%, dur unchanged).
//  Fix: direct-to-LDS DMA staging (zero staging VGPRs, zero staging VALU,
//  no register round-trip). fp32 in LDS costs the same bytes as bf16 hi+lo,
//  so frag-read traffic is unchanged (10x b128/step/wave); conversion moves
//  into COMPUTE, spread over all 64 lanes on the 80%-idle VALU pipe.
//  - LDS panel layout: [8 groups(4ch)][64 px][4 ch] fp32, group pitch 1040 B
//    (+16 pad spreads groups across banks). Transpose folded into the
//    per-lane GLOBAL source address (DMA LDS dest is linear wave-uniform
//    base + lane*4; source is per-lane). 16 DMA chunks of 256 B per wave
//    per panel.
//  - Norms for free: frag reads touch every (px,ch) fp32; accumulate x*x on
//    loaded values, shfl_xor over kc at the end. Exact fp32.
//  - Loop: STAGE(k+1 -> buf^1) async DMA at step top; COMPUTE(k);
//    s_waitcnt vmcnt(0) lgkmcnt(0); s_barrier. One barrier per step.
//  - MFMA math identical to v7 (verified): D = base^T.mom per batch,
//    mfma_f32_16x16x32_bf16, Ahi.Bhi + Ahi.Blo + Alo.Bhi.

constexpr int NB  = 2048;
constexpr int NC  = 256;
constexpr int NP  = 49;
constexpr float EPS = 1e-6f;

constexpr int GPW  = 260;           // group pitch in words (1040 B: 1024 + 16 pad)
constexpr int FSW  = 8 * GPW;       // feature stride in words (2080)
constexpr int BUFW = 2 * FSW;       // buffer stride in words (4160)
constexpr int PSTR = 32 * NP;       // global panel stride in floats (1568)

typedef short bf16x8 __attribute__((ext_vector_type(8)));   // 8 bf16 = 4 VGPR
typedef float f32x4  __attribute__((ext_vector_type(4)));   // mfma accumulator
typedef unsigned int uix4 __attribute__((ext_vector_type(4)));

// global fp32 -> LDS dword DMA; offset arg is literal 0 (displacements are
// folded into SRC/DST pointers). LDS dest wave-uniform; source per-lane.
#define GLD(SRC, DST)                                                        \
    __builtin_amdgcn_global_load_lds(                                        \
        (const __attribute__((address_space(1))) unsigned int*)(SRC),        \
        (__attribute__((address_space(3))) unsigned int*)(DST), 4, 0, 0)

__global__ __launch_bounds__(256, 2)
void pixpro_kernel(const float* __restrict__ gbase,
                   const float* __restrict__ gmom,
                   const int*   __restrict__ A1,
                   const int*   __restrict__ A2,
                   float*       __restrict__ out)
{
    __shared__ unsigned char wtb[NP * NP];            // weights u8 {0,1,2}
    __shared__ __align__(16) float mats[2 * BUFW];    // 33280 B: 2 buffers
    __shared__ float sbc[NP], smc[NP];                // combined sq-norms
    __shared__ float redsum[4];

    const int tid  = threadIdx.x;
    const int wave = tid >> 6;
    const int lane = tid & 63;
    const int b    = blockIdx.x;

    // --- stage combined mask weights ---
    for (int t = tid; t < NP * NP; t += 256) {
        int p = t / NP, q = t - p * NP;
        wtb[t] = (unsigned char)((A1[t] == 1 ? 1 : 0) + (A2[q * NP + p] == 1 ? 1 : 0));
    }

    const float* gB = gbase + (size_t)b * (NC * NP);
    const float* gM = gmom  + (size_t)b * (NC * NP);

    // per-lane DMA sources (wave w stages channels 8w..8w+7 of each panel)
    // instr (gl,i4): ch = 8w + 4*gl + (lane&3), px = 16*i4 + (lane>>2) (i4<3)
    // i4==3 rows are the 49..63 tail: all lanes fetch pixel 48 (defined garbage).
    const int ch0 = 8 * wave + (lane & 3);
    const int px0 = lane >> 2;
    const float* srcAb = gB + ch0 * NP + px0;   // i4 = 0..2 (+16 px per i4)
    const float* src3b = gB + ch0 * NP + 48;    // i4 = 3 (clamped row)
    const float* srcAm = gM + ch0 * NP + px0;
    const float* src3m = gM + ch0 * NP + 48;

    int stg_buf = 0;   // word offset of the buffer the NEXT stage writes

    auto STAGE = [&]() {
        float* const d0 = mats + stg_buf + (2 * wave) * GPW;   // base feature
        float* const d1 = d0 + FSW;                            // mom feature
        #pragma unroll
        for (int gl = 0; gl < 2; ++gl) {
            GLD(srcAb + gl * 196 +  0, d0 + gl * GPW +   0);
            GLD(srcAb + gl * 196 + 16, d0 + gl * GPW +  64);
            GLD(srcAb + gl * 196 + 32, d0 + gl * GPW + 128);
            GLD(src3b + gl * 196,      d0 + gl * GPW + 192);
        }
        #pragma unroll
        for (int gl = 0; gl < 2; ++gl) {
            GLD(srcAm + gl * 196 +  0, d1 + gl * GPW +   0);
            GLD(srcAm + gl * 196 + 16, d1 + gl * GPW +  64);
            GLD(srcAm + gl * 196 + 32, d1 + gl * GPW + 128);
            GLD(src3m + gl * 196,      d1 + gl * GPW + 192);
        }
        srcAb += PSTR; src3b += PSTR; srcAm += PSTR; src3m += PSTR;
        stg_buf ^= BUFW;
    };

    const int fr = lane & 15;     // frag row/col within tile
    const int kc = lane >> 4;     // k-chunk (8 channels)

    f32x4 acc[4];
    const f32x4 zz = {0.f, 0.f, 0.f, 0.f};
    acc[0] = zz; acc[1] = zz; acc[2] = zz; acc[3] = zz;
    float nb = 0.f;
    float nm[4] = {0.f, 0.f, 0.f, 0.f};

    // split 8 fp32 into packed bf16 hi/lo words; accumulate exact sq-norm
    auto CVT8 = [&](float4 L, float4 H, unsigned int (&hw)[4],
                    unsigned int (&lw)[4], float& na) {
        float xs[8] = {L.x, L.y, L.z, L.w, H.x, H.y, H.z, H.w};
        #pragma unroll
        for (int jp = 0; jp < 4; ++jp) {
            float x0 = xs[2 * jp], x1 = xs[2 * jp + 1];
            unsigned int u0 = __float_as_uint(x0) & 0xFFFF0000u;
            unsigned int u1 = __float_as_uint(x1) & 0xFFFF0000u;
            hw[jp] = u1 | (u0 >> 16);
            float l0 = x0 - __uint_as_float(u0);
            float l1 = x1 - __uint_as_float(u1);
            unsigned int r;
            asm("v_cvt_pk_bf16_f32 %0, %1, %2" : "=v"(r) : "v"(l0), "v"(l1));
            lw[jp] = r;
            na = fmaf(x0, x0, fmaf(x1, x1, na));
        }
    };
    auto PACK = [](const unsigned int (&w)[4]) {
        uix4 t; t[0] = w[0]; t[1] = w[1]; t[2] = w[2]; t[3] = w[3];
        return *(const bf16x8*)&t;
    };

    auto COMPUTE = [&](int bufw) {
        // A-frag: base pixel 16w+fr, channels 8kc..8kc+7 (groups 2kc, 2kc+1)
        const float* pa = mats + bufw + (2 * kc) * GPW + (16 * wave + fr) * 4;
        float4 aL = *(const float4*)(pa);
        float4 aH = *(const float4*)(pa + GPW);
        unsigned int ahw[4], alw[4];
        CVT8(aL, aH, ahw, alw, nb);
        bf16x8 Ah = PACK(ahw), Al = PACK(alw);
        // B-frags: mom pixel 16t+fr, channels 8kc..8kc+7
        const float* pb = mats + bufw + FSW + (2 * kc) * GPW + fr * 4;
        #pragma unroll
        for (int t = 0; t < 4; ++t) {
            float4 bL = *(const float4*)(pb + t * 64);
            float4 bH = *(const float4*)(pb + t * 64 + GPW);
            unsigned int bhw[4], blw[4];
            CVT8(bL, bH, bhw, blw, nm[t]);
            bf16x8 Bh = PACK(bhw), Bl = PACK(blw);
            acc[t] = __builtin_amdgcn_mfma_f32_16x16x32_bf16(Ah, Bh, acc[t], 0, 0, 0);
            acc[t] = __builtin_amdgcn_mfma_f32_16x16x32_bf16(Ah, Bl, acc[t], 0, 0, 0);
            acc[t] = __builtin_amdgcn_mfma_f32_16x16x32_bf16(Al, Bh, acc[t], 0, 0, 0);
        }
    };

    // --- prologue: stage panel 0 ---
    STAGE();
    asm volatile("s_waitcnt vmcnt(0)" ::: "memory");
    __syncthreads();

    // --- 8 k-steps: async DMA prefetch at top, one barrier per step ---
    #pragma unroll 2
    for (int k = 0; k < 8; ++k) {
        if (k < 7) STAGE();
        __builtin_amdgcn_sched_barrier(0);
        COMPUTE((k & 1) * BUFW);
        asm volatile("s_waitcnt vmcnt(0) lgkmcnt(0)" ::: "memory");
        __builtin_amdgcn_s_barrier();
        __builtin_amdgcn_sched_barrier(0);
    }

    // --- norm reduction: sum the kc quarters (lanes stride 16) ---
    nb += __shfl_xor(nb, 16, 64);
    nb += __shfl_xor(nb, 32, 64);
    #pragma unroll
    for (int t = 0; t < 4; ++t) {
        nm[t] += __shfl_xor(nm[t], 16, 64);
        nm[t] += __shfl_xor(nm[t], 32, 64);
    }
    if (lane < 16) {                      // base pixel 16w+lane (wave-split)
        int p = 16 * wave + lane;
        if (p < NP) sbc[p] = nb;
    }
    if (wave == 0 && lane < 16) {         // mom pixels (every wave has full copy)
        #pragma unroll
        for (int t = 0; t < 4; ++t) {
            int p = 16 * t + lane;
            if (p < NP) smc[p] = nm[t];
        }
    }
    __syncthreads();

    // --- epilogue: lane holds D[16w + 4*kc + r][16t + fr] in acc[t][r] ---
    float nbr[4];
    #pragma unroll
    for (int r = 0; r < 4; ++r) {
        int row = 16 * wave + 4 * kc + r;
        nbr[r] = (row < NP) ? sqrtf(sbc[row]) : 0.f;
    }
    float sum = 0.f;
    #pragma unroll
    for (int t = 0; t < 4; ++t) {
        int col = 16 * t + fr;
        if (col < NP) {
            float nmc = sqrtf(smc[col]);
            #pragma unroll
            for (int r = 0; r < 4; ++r) {
                int row = 16 * wave + 4 * kc + r;
                if (row < NP) {
                    float w     = (float)wtb[row * NP + col];
                    float denom = fmaxf(nbr[r] * nmc, EPS);
                    sum += w * acc[t][r] / denom;
                }
            }
        }
    }
    #pragma unroll
    for (int m = 32; m; m >>= 1) sum += __shfl_xor(sum, m, 64);
    if (lane == 0) redsum[wave] = sum;
    __syncthreads();
    if (tid == 0)
        out[b] = -(redsum[0] + redsum[1] + redsum[2] + redsum[3]) * (1.0f / 2401.0f);
}

extern "C" void kernel_launch(void* const* d_in, const int* in_sizes, int n_in,
                              void* d_out, int out_size, void* d_ws, size_t ws_size,
                              hipStream_t stream)
{
    (void)in_sizes; (void)n_in; (void)d_ws; (void)ws_size; (void)out_size;
    const float* base = (const float*)d_in[0];
    const float* mom  = (const float*)d_in[1];
    const int*   A1   = (const int*)d_in[2];
    const int*   A2   = (const int*)d_in[3];
    float*       out  = (float*)d_out;

    pixpro_kernel<<<NB, 256, 0, stream>>>(base, mom, A1, A2, out);
}